// Round 18
// baseline (104.518 us; speedup 1.0000x reference)
//
#include <hip/hip_runtime.h>

// CRF NLL: 5-way segmented chains with rank-1 bridges -- ALL 8 CHAINS OF
// A BATCH ON ONE CU, PAIRED 2-PER-WAVE WITH MANUAL INTERLEAVE (R30;
// resubmitted verbatim -- R16/R17 slots both hit GPU-acquisition
// timeouts; the kernel has never run).
//   R29 post-mortem: sequential fstep();bstep() calls did NOT interleave
//   (1280 cyc/pair-slot = 640/chain-step, worse than a lone chain's 408)
//   -- the compiler scheduled each 34-readlane dot + dependent tail as a
//   unit. R13's ~700/pair came from INSTRUCTION-LEVEL interleave. Cost
//   model (consistent across R13/R14/R21/R22/R29): readlane = ~9cyc of
//   un-hideable issue occupancy; pair floor ~= 68*9 + tail ~= 700/pair,
//   the pairing amortizing all non-readlane latency across two chains.
//   R30 = R29 with a single pstep() alternating FDOT(n)/BDOT(n) per
//   term. Both broadcast sources (q, pp) are fixed at step entry ->
//   68 independent readlanes; per-chain accumulation order unchanged ->
//   bit-identical arithmetic to R29 (passed, absmax 0.0).
//   Also measured in R29: single-kernel overhead ~45us vs two-kernel
//   ~57us -> stay fused (LDS meet, no device fences -- R28's fence
//   L2-invalidation disaster stays dead).
// Chain math (R21/R22, harness-verified): c = ceil((len-1)/5):
//   wave 0: real fwd alpha (t=1..c) + real bwd gamma (tau=len-1..4c+1)
//   wave w=1..3: fwd probe y_w (chunk w; u=1, u[START]=0)
//                + bwd probe z_w (chunk w; v=1, v[END]=0)
//   meet: log Z = C_a + C_z1..3 + C_g + log(z1.a) + log(z2.y1)
//       + log(z3.y2) + log(g.y3) - log(sum y1..y3)

namespace {
constexpr int kB = 128;
constexpr int kS = 512;
constexpr int kT = 36;
constexpr int kStart = 34;
constexpr int kEnd = 35;

__device__ __forceinline__ float readlane_f(float v, int lane) {
    return __builtin_bit_cast(float, __builtin_amdgcn_readlane(__builtin_bit_cast(int, v), lane));
}

__device__ __forceinline__ float wave_sum(float v) {
#pragma unroll
    for (int off = 32; off; off >>= 1) v += __shfl_xor(v, off, 64);
    return v;
}
__device__ __forceinline__ int wave_sum_i(int v) {
#pragma unroll
    for (int off = 32; off; off >>= 1) v += __shfl_xor(v, off, 64);
    return v;
}

// n = term index, a = accumulator index (rotates 0..3 to break fma chains)
#define FOR34(X) \
    X(0, 0) X(1, 1) X(2, 2) X(3, 3) X(4, 0) X(5, 1) X(6, 2) X(7, 3) \
    X(8, 0) X(9, 1) X(10, 2) X(11, 3) X(12, 0) X(13, 1) X(14, 2) X(15, 3) \
    X(16, 0) X(17, 1) X(18, 2) X(19, 3) X(20, 0) X(21, 1) X(22, 2) X(23, 3) \
    X(24, 0) X(25, 1) X(26, 2) X(27, 3) X(28, 0) X(29, 1) X(30, 2) X(31, 3) \
    X(32, 0) X(33, 1)

#define FMDECL(n, a) float Fm##n;
#define FMINIT(n, a) Fm##n = __expf(trans[(n)*kT + jc]);
#define BMDECL(n, a) float Bm##n;
#define BMINIT(n, a) Bm##n = __expf(trans[jc * kT + (n)]);
// manually interleaved pair-dot: alternating independent readlane streams
#define PDOT(n, a) \
    v##a = fmaf(readlane_f(q, n), Fm##n, v##a); \
    w##a = fmaf(readlane_f(pp, n), Bm##n, w##a);

// clamped feats row load (clamped values only feed predicated-off pad steps)
#define LDT(t) fl[(size_t)(((t) < 0) ? 0 : (((t) > kS - 1) ? (kS - 1) : (t))) * kT]

__device__ __forceinline__ int seq_len(const int* mb, int j) {
    int len = 0;
#pragma unroll
    for (int k = 0; k < kS / 64; ++k) len += mb[k * 64 + j];
    return __builtin_amdgcn_readfirstlane(wave_sum_i(len));
}

__global__ __attribute__((amdgpu_flat_work_group_size(256, 256),
                          amdgpu_waves_per_eu(1, 1)))
void crf_pair_kernel(const float* __restrict__ feats,   // (B,S,T)
                     const float* __restrict__ trans,   // (T,T)
                     const int* __restrict__ mask,      // (B,S)
                     const int* __restrict__ tags,      // (B,S)
                     float* __restrict__ out) {         // scalar
    const int b = blockIdx.x;
    const int tid = threadIdx.x;
    const int w = tid >> 6;                   // wave 0..3 (one per SIMD)
    const int j = tid & 63;                   // lane = state index
    const int jc = (j < kT) ? j : (kT - 1);   // clamped (addressing only)
    const float* fbase = feats + (size_t)b * kS * kT;
    const float* fl = fbase + jc;             // per-lane feats column
    const int* mb = mask + b * kS;
    const int* tb = tags + b * kS;

    __shared__ float xq[4][64];   // fwd results: alpha, y1, y2, y3
    __shared__ float xg[4][64];   // bwd results: gamma, z1, z2, z3
    __shared__ float cqb[4], cgb[4];

    const int len = seq_len(mb, j);           // in [256, 512]
    const int c = (len + 3) / 5;              // ceil((len-1)/5), in [51, 103]
    const int Gp = (c + 3) >> 2;              // 4-step groups covering c steps

    // ---- both coefficient sets (this wave runs one fwd + one bwd chain) --
    FOR34(FMDECL) FOR34(FMINIT)
    FOR34(BMDECL) FOR34(BMINIT)

    // ---- fwd chain init (w=0 real alpha, w>=1 probe y_w) ----
    const int t0f = 1 + w * c;
    const int cntf = c;
    float q, Cq = 0.f;
    if (w == 0) {
        const float a0 = (j < kT) ? (fl[0] + trans[kStart * kT + jc]) : -1e30f;
        Cq = readlane_f(a0, 0);
        q = __expf(a0 - Cq);
    } else {
        q = (jc == kStart) ? 0.f : 1.f;       // u, u[START]=0
    }

    // ---- bwd chain init (w=0 real gamma, w>=1 probe z_w) ----
    const bool real = (w == 0);
    const int tau0 = real ? (len - 1) : ((w + 1) * c);
    const int cntb = real ? (len - 1 - 4 * c) : c;   // in [c-4, c]
    float gg = real ? __expf(trans[jc * kT + kEnd])  // g[END]=0 exactly
                    : ((jc == kEnd) ? 0.f : 1.f);    // v, v[END]=0
    float Cg = 0.f;

    // one interleaved pair-step: both chains advance; per-chain FP order
    // identical to R22/R29 (accumulator rotation v(n%4)/w(n%4))
    auto pstep = [&](float ef, float eb, int s) {
        const float pp = eb * gg;
        float v0 = 0.f, v1 = 0.f, v2 = 0.f, v3 = 0.f;
        float w0 = 0.f, w1 = 0.f, w2 = 0.f, w3 = 0.f;
        FOR34(PDOT)
        const float nq = ((v0 + v1) + (v2 + v3)) * ef;
        const float ng = (w0 + w1) + (w2 + w3);
        q = (s < cntf) ? nq : q;              // pad steps hold
        gg = (s < cntb) ? ng : gg;
    };

    // ---- dual prefetch pipelines (one group lookahead each, as R29) ----
    float pf0, pf1, pf2, pf3, ef0, ef1, ef2, ef3;
    float pb0, pb1, pb2, pb3, eb0, eb1, eb2, eb3;
    pf0 = LDT(t0f + 0); pf1 = LDT(t0f + 1); pf2 = LDT(t0f + 2); pf3 = LDT(t0f + 3);
    ef0 = __expf(pf0); ef1 = __expf(pf1); ef2 = __expf(pf2); ef3 = __expf(pf3);
    pf0 = LDT(t0f + 4); pf1 = LDT(t0f + 5); pf2 = LDT(t0f + 6); pf3 = LDT(t0f + 7);
    pb0 = LDT(tau0 - 0); pb1 = LDT(tau0 - 1); pb2 = LDT(tau0 - 2); pb3 = LDT(tau0 - 3);
    eb0 = __expf(pb0); eb1 = __expf(pb1); eb2 = __expf(pb2); eb3 = __expf(pb3);
    pb0 = LDT(tau0 - 4); pb1 = LDT(tau0 - 5); pb2 = LDT(tau0 - 6); pb3 = LDT(tau0 - 7);

#pragma unroll 1
    for (int g = 0; g < Gp; ++g) {
        const int s = 4 * g;
        pstep(ef0, eb0, s);
        pstep(ef1, eb1, s + 1);
        pstep(ef2, eb2, s + 2);
        pstep(ef3, eb3, s + 3);
        ef0 = __expf(pf0); ef1 = __expf(pf1); ef2 = __expf(pf2); ef3 = __expf(pf3);
        pf0 = LDT(t0f + s + 8);  pf1 = LDT(t0f + s + 9);
        pf2 = LDT(t0f + s + 10); pf3 = LDT(t0f + s + 11);
        eb0 = __expf(pb0); eb1 = __expf(pb1); eb2 = __expf(pb2); eb3 = __expf(pb3);
        pb0 = LDT(tau0 - s - 8);  pb1 = LDT(tau0 - s - 9);
        pb2 = LDT(tau0 - s - 10); pb3 = LDT(tau0 - s - 11);
        if (s + 4 < cntf) {   // fold renorm only into an ACTIVE next step
            const float mf = readlane_f(q, 0);
            Cq += __logf(mf);
            ef0 *= __builtin_amdgcn_rcpf(mf);
        }
        if (s + 4 < cntb) {
            const float mg = readlane_f(gg, 0);
            Cg += __logf(mg);
            eb0 *= __builtin_amdgcn_rcpf(mg);
        }
    }

    xq[w][j] = q;   // alpha, y1, y2, y3
    xg[w][j] = gg;  // gamma, z1, z2, z3
    if (j == 0) { cqb[w] = Cq; cgb[w] = Cg; }
    __syncthreads();

    if (w == 0) {
        // ---- meet via rank-1 bridges (lanes >= 36 masked out) ----
        const float msk = (j < kT) ? 1.f : 0.f;
        const float d1 = wave_sum(msk * xg[1][j] * xq[0][j]);  // z1 . alpha
        const float d2 = wave_sum(msk * xg[2][j] * xq[1][j]);  // z2 . y1
        const float d3 = wave_sum(msk * xg[3][j] * xq[2][j]);  // z3 . y2
        const float d4 = wave_sum(msk * xg[0][j] * xq[3][j]);  // gamma . y3
        const float n1 = wave_sum(msk * xq[1][j]);             // sum y1
        const float n2 = wave_sum(msk * xq[2][j]);
        const float n3 = wave_sum(msk * xq[3][j]);
        const float forward_b = cqb[0] + cgb[1] + cgb[2] + cgb[3] + cgb[0]
            + __logf(d1) + __logf(d2) + __logf(d3) + __logf(d4)
            - __logf(n1) - __logf(n2) - __logf(n3);

        // ---- gold score (parallel over time steps) ----
        float gold = 0.f;
        for (int k = j; k < kS; k += 64) {
            if (k < len) {
                const int tg = tb[k];
                const int pv = (k == 0) ? kStart : tb[k - 1];
                gold += fbase[(size_t)k * kT + tg] + trans[pv * kT + tg];
            }
        }
        gold = wave_sum(gold);

        if (j == 0) {
            gold += trans[tb[len - 1] * kT + kEnd];
            atomicAdd(out, (forward_b - gold) * (1.0f / kB));
        }
    }
}

}  // namespace

extern "C" void kernel_launch(void* const* d_in, const int* in_sizes, int n_in,
                              void* d_out, int out_size, void* d_ws, size_t ws_size,
                              hipStream_t stream) {
    const float* feats = (const float*)d_in[0];
    const float* trans = (const float*)d_in[1];
    const int* mask = (const int*)d_in[2];
    const int* tags = (const int*)d_in[3];
    float* out = (float*)d_out;

    (void)hipMemsetAsync(out, 0, sizeof(float), stream);
    crf_pair_kernel<<<dim3(kB), dim3(256), 0, stream>>>(feats, trans, mask, tags, out);
}